// Round 12
// baseline (780.163 us; speedup 1.0000x reference)
//
#include <hip/hip_runtime.h>
#include <cstdint>
#include <utility>

#define NQ 16
#define NDEPTH 4
#define NBATCH 512
#define NTHR 512      // threads per block (8 waves = 2 waves/SIMD, pinned)
#define NAMP 128      // amps per thread (65536 / NTHR)
#define NREG 97       // amps in registers (194 VGPRs)
#define NLDS (NAMP - NREG)   // 31 amps in LDS: 31*512*8 = 124 KB

typedef float vf2 __attribute__((ext_vector_type(2)));
typedef float vf4 __attribute__((ext_vector_type(4)));

// ---------------------------------------------------------------------------
// Compile-time GF(2) tracking of the CNOT ring (verified r1/r4/r6-r9/r11,
// passes at absmax 6.1e-5).  Physical index x (16 bits): bit b <-> wire 15-b.
// Rotation on logical wire q at layer d:
//   pair mask  Delta = A^{-1} e_p, parity row R = row_p(A), p = 15-q.
// Layout: x = (tid << 7) | r ; reg = x[6:0], lane = tid[5:0], wave = tid[8:6].
// C-gate (wave-crossing) dregs: {0,1,2,3,7}.  B-gate dlanes include
// DPP-expressible XORs {1,2,3,7,15} (10 of 24 gates).
// ---------------------------------------------------------------------------
struct Masks {
  unsigned short delta[NDEPTH][NQ];
  unsigned short rowm[NDEPTH][NQ];
  unsigned short meas[NQ];
};

constexpr Masks make_masks() {
  Masks m = {};
  unsigned short Arow[NQ] = {};
  unsigned short Ainv[NQ] = {};
  for (int p = 0; p < NQ; ++p) {
    Arow[p] = (unsigned short)(1u << p);
    Ainv[p] = (unsigned short)(1u << p);
  }
  for (int d = 0; d < NDEPTH; ++d) {
    for (int q = 0; q < NQ; ++q) {
      m.delta[d][q] = Ainv[15 - q];
      m.rowm[d][q]  = Arow[15 - q];
    }
    for (int q = 0; q < NQ - 1; ++q) {    // CNOT(q, q+1)
      const int pc = 15 - q, pt = 15 - (q + 1);
      Arow[pt] = (unsigned short)(Arow[pt] ^ Arow[pc]);
      Ainv[pc] = (unsigned short)(Ainv[pc] ^ Ainv[pt]);
    }
    {                                      // CNOT(15, 0)
      const int pc = 0, pt = 15;
      Arow[pt] = (unsigned short)(Arow[pt] ^ Arow[pc]);
      Ainv[pc] = (unsigned short)(Ainv[pc] ^ Ainv[pt]);
    }
  }
  for (int q = 0; q < NQ; ++q) m.meas[q] = Arow[15 - q];
  return m;
}

constexpr Masks MK = make_masks();

constexpr int cpar(int v) {
  int p = 0;
  for (int i = 0; i < 16; ++i) p ^= (v >> i) & 1;
  return p;
}

// DPP ctrl encoding for lane-XOR patterns expressible in one v_mov_dpp:
//  xor1 = quad_perm[1,0,3,2] = 0xB1 ; xor2 = [2,3,0,1] = 0x4E ;
//  xor3 = [3,2,1,0] = 0x1B ; xor7 = ROW_HALF_MIRROR 0x141 ;
//  xor15 = ROW_MIRROR 0x140.  Others: -1 (fall back to shuffle).
constexpr int dppctrl(int dl) {
  return dl == 1 ? 0xB1 : dl == 2 ? 0x4E : dl == 3 ? 0x1B
       : dl == 7 ? 0x141 : dl == 15 ? 0x140 : -1;
}

template<typename F, int... Is>
__device__ __forceinline__ void sf_impl(F&& f, std::integer_sequence<int, Is...>) {
  (f(std::integral_constant<int, Is>{}), ...);
}
template<int N, typename F>
__device__ __forceinline__ void static_for(F&& f) {
  sf_impl(f, std::make_integer_sequence<int, N>{});
}

// new = A*m + B*p (complex), coeffs pre-expanded: Arr=(A.re,A.re),
// Ain=(-A.im,A.im), Brr=(B.re,B.re), Bin=(-B.im,B.im).
// 4 VOP3P instructions; the complex cross-terms use op_sel half-swaps:
//   res.lo = Ain.lo*m.hi + t.lo  (op_sel src1=1)
//   res.hi = Ain.hi*m.lo + t.hi  (op_sel_hi src1=0)
__device__ __forceinline__ vf2 upd(vf2 Arr, vf2 Ain, vf2 Brr, vf2 Bin,
                                   vf2 m, vf2 p) {
  vf2 t;
  asm("v_pk_mul_f32 %0, %1, %2\n\t"
      "v_pk_fma_f32 %0, %3, %2, %0 op_sel:[0,1,0] op_sel_hi:[1,0,1]\n\t"
      "v_pk_fma_f32 %0, %4, %5, %0\n\t"
      "v_pk_fma_f32 %0, %6, %5, %0 op_sel:[0,1,0] op_sel_hi:[1,0,1]"
      : "=&v"(t)
      : "v"(Arr), "v"(m), "v"(Ain), "v"(Brr), "v"(p), "v"(Bin));
  return t;
}

// lane-XOR exchange: DPP (VALU pipe, no DS op) when expressible, else shuffle
template<int DL>
__device__ __forceinline__ vf2 xlane(vf2 v) {
  constexpr int C = dppctrl(DL);
  if constexpr (C >= 0) {
    int xi = __float_as_int(v.x), yi = __float_as_int(v.y);
    xi = __builtin_amdgcn_update_dpp(xi, xi, C, 0xF, 0xF, true);
    yi = __builtin_amdgcn_update_dpp(yi, yi, C, 0xF, 0xF, true);
    return (vf2){__int_as_float(xi), __int_as_float(yi)};
  } else {
    vf2 p;
    p.x = __shfl_xor(v.x, DL);
    p.y = __shfl_xor(v.y, DL);
    return p;
  }
}

// ---- compile-time-dispatched state accessors: reg for r<NREG, LDS above ----
template<int r>
__device__ __forceinline__ vf2 getamp(const vf2 (&s)[NREG], const vf2* sst, int tid) {
  if constexpr (r < NREG) return s[r];
  else return sst[(r - NREG) * NTHR + tid];
}
template<int r>
__device__ __forceinline__ void putamp(vf2 (&s)[NREG], vf2* sst, int tid, vf2 v) {
  if constexpr (r < NREG) s[r] = v;
  else sst[(r - NREG) * NTHR + tid] = v;
}
template<int r>
__device__ __forceinline__ vf4 pack2(const vf2 (&s)[NREG], const vf2* sst, int tid) {
  const vf2 a = getamp<r    >(s, sst, tid);
  const vf2 b = getamp<r + 1>(s, sst, tid);
  return (vf4){a.x, a.y, b.x, b.y};
}

// ---------------------------------------------------------------------------
// One rotation gate.  Element of total parity b (= constexpr reg-parity ^
// runtime thread-parity pt): new = U[b][b]*mine + U[b][1-b]*partner.
// Coefficients pre-expanded in LDS as float4 pairs; the set for each parity
// is chosen by pt via the LDS address (b128 loads, no selects).
// ---------------------------------------------------------------------------
template<int D, int Q>
__device__ __forceinline__ void apply_gate(vf2 (&s)[NREG], vf2* sst, vf4* xch,
                                           const vf4* utab, int tid) {
  constexpr int DLT   = MK.delta[D][Q];
  constexpr int R     = MK.rowm[D][Q];
  constexpr int dreg  = DLT & (NAMP - 1);
  constexpr int dthr  = DLT >> 7;
  constexpr int dlane = dthr & 63;
  constexpr int dwave = dthr >> 6;

  const int pt = __popc(tid & (R >> 7)) & 1;
  const int gbase = (D * NQ + Q) * 4;
  const int o0 = pt << 1;                 // float4 offset of set for reg-parity 0
  const int o1 = 2 - o0;                  // set for reg-parity 1
  const vf4 ca0 = utab[gbase + o0], cb0 = utab[gbase + o0 + 1];
  const vf4 ca1 = utab[gbase + o1], cb1 = utab[gbase + o1 + 1];
  const vf2 A0rr = {ca0.x, ca0.y}, A0in = {ca0.z, ca0.w};
  const vf2 B0rr = {cb0.x, cb0.y}, B0in = {cb0.z, cb0.w};
  const vf2 A1rr = {ca1.x, ca1.y}, A1in = {ca1.z, ca1.w};
  const vf2 B1rr = {cb1.x, cb1.y}, B1in = {cb1.z, cb1.w};

  if constexpr (dthr == 0) {
    // ---- Case A: pair entirely within this thread; fence per 32 amps ----
    static_for<4>([&](auto bc) {
      constexpr int BB = decltype(bc)::value;
      static_for<32>([&](auto jc) {
        constexpr int r = 32 * BB + decltype(jc)::value;
        constexpr int r2 = r ^ dreg;
        if constexpr (r < r2) {
          constexpr int p0 = cpar(r & R);
          constexpr int p1 = cpar(r2 & R);   // explicit (r3 lesson)
          const vf2 a = getamp<r >(s, sst, tid);
          const vf2 c = getamp<r2>(s, sst, tid);
          const vf2 n0 = p0 ? upd(A1rr, A1in, B1rr, B1in, a, c)
                             : upd(A0rr, A0in, B0rr, B0in, a, c);
          const vf2 n1 = p1 ? upd(A1rr, A1in, B1rr, B1in, c, a)
                             : upd(A0rr, A0in, B0rr, B0in, c, a);
          putamp<r >(s, sst, tid, n0);
          putamp<r2>(s, sst, tid, n1);
        }
      });
      __builtin_amdgcn_sched_barrier(0);
    });
  } else if constexpr (dwave == 0) {
    // ---- Case B: partner in same wave -> DPP/shuffle; fence per 32 amps ----
    if constexpr (dreg == 0) {
      static_for<4>([&](auto bc) {
        constexpr int BB = decltype(bc)::value;
        static_for<32>([&](auto jc) {
          constexpr int r = 32 * BB + decltype(jc)::value;
          constexpr int p0 = cpar(r & R);
          const vf2 m = getamp<r>(s, sst, tid);
          const vf2 p = xlane<dlane>(m);
          const vf2 n = p0 ? upd(A1rr, A1in, B1rr, B1in, m, p)
                            : upd(A0rr, A0in, B0rr, B0in, m, p);
          putamp<r>(s, sst, tid, n);
        });
        __builtin_amdgcn_sched_barrier(0);
      });
    } else {
      static_for<4>([&](auto bc) {
        constexpr int BB = decltype(bc)::value;
        static_for<32>([&](auto jc) {
          constexpr int r = 32 * BB + decltype(jc)::value;
          constexpr int r2 = r ^ dreg;
          if constexpr (r < r2) {
            constexpr int p0 = cpar(r & R);
            constexpr int p1 = cpar(r2 & R);
            const vf2 m0 = getamp<r >(s, sst, tid);
            const vf2 m1 = getamp<r2>(s, sst, tid);
            const vf2 p0v = xlane<dlane>(m1);   // partner's amp r^dreg
            const vf2 p1v = xlane<dlane>(m0);   // partner's amp r
            const vf2 n0 = p0 ? upd(A1rr, A1in, B1rr, B1in, m0, p0v)
                               : upd(A0rr, A0in, B0rr, B0in, m0, p0v);
            const vf2 n1 = p1 ? upd(A1rr, A1in, B1rr, B1in, m1, p1v)
                               : upd(A0rr, A0in, B0rr, B0in, m1, p1v);
            putamp<r >(s, sst, tid, n0);
            putamp<r2>(s, sst, tid, n1);
          }
        });
        __builtin_amdgcn_sched_barrier(0);
      });
    }
  } else {
    // ---- Case C: partner in another wave -> barrier-staged b128 exchange ----
    // 8 amps per round (chunks c, c^kc through 4 b128 slots), 2 barriers,
    // 16 rounds per gate.
    constexpr int kc0 = dreg >> 2;
    constexpr int kc  = kc0 ? kc0 : 1;
    const int ptid = tid ^ dthr;
    static_for<NAMP / 4>([&](auto cc) {
      constexpr int c = decltype(cc)::value;
      if constexpr (c < (c ^ kc)) {
        constexpr int c2 = c ^ kc;
        // stage own 8 amps: slots 0,1 = chunk c ; slots 2,3 = chunk c2
        xch[0 * NTHR + tid] = pack2<4 * c  + 0>(s, sst, tid);
        xch[1 * NTHR + tid] = pack2<4 * c  + 2>(s, sst, tid);
        xch[2 * NTHR + tid] = pack2<4 * c2 + 0>(s, sst, tid);
        xch[3 * NTHR + tid] = pack2<4 * c2 + 2>(s, sst, tid);
        __syncthreads();
        const vf4 q0 = xch[0 * NTHR + ptid];
        const vf4 q1 = xch[1 * NTHR + ptid];
        const vf4 q2 = xch[2 * NTHR + ptid];
        const vf4 q3 = xch[3 * NTHR + ptid];
        static_for<8>([&](auto jc) {
          constexpr int jj = decltype(jc)::value;
          constexpr int r  = (jj < 4) ? (4 * c + jj) : (4 * c2 + (jj - 4));
          constexpr int rp = r ^ dreg;            // partner amp index
          constexpr int sb = ((rp >> 2) == c) ? 0 : 2;
          constexpr int slot = sb + ((rp & 3) >> 1);
          constexpr int half = rp & 1;
          constexpr int p0 = cpar(r & R);
          vf2 p;
          if constexpr (slot == 0)      p = half ? (vf2){q0.z, q0.w} : (vf2){q0.x, q0.y};
          else if constexpr (slot == 1) p = half ? (vf2){q1.z, q1.w} : (vf2){q1.x, q1.y};
          else if constexpr (slot == 2) p = half ? (vf2){q2.z, q2.w} : (vf2){q2.x, q2.y};
          else                          p = half ? (vf2){q3.z, q3.w} : (vf2){q3.x, q3.y};
          const vf2 m = getamp<r>(s, sst, tid);
          const vf2 n = p0 ? upd(A1rr, A1in, B1rr, B1in, m, p)
                            : upd(A0rr, A0in, B0rr, B0in, m, p);
          putamp<r>(s, sst, tid, n);
        });
        __syncthreads();
      }
    });
  }
}

template<int D, int Q>
__device__ __forceinline__ void apply_all(vf2 (&s)[NREG], vf2* sst, vf4* xch,
                                          const vf4* utab, int tid) {
  apply_gate<D, Q>(s, sst, xch, utab, tid);
  __builtin_amdgcn_sched_barrier(0);   // no cross-gate scheduling overlap
  if constexpr (Q < NQ - 1) {
    apply_all<D, Q + 1>(s, sst, xch, utab, tid);
  } else if constexpr (D < NDEPTH - 1) {
    apply_all<D + 1, 0>(s, sst, xch, utab, tid);
  }
}

// 8-wave block, LDS 160 KiB -> 1 block/CU -> exactly 2 waves/SIMD.
__global__ __launch_bounds__(NTHR)
__attribute__((amdgpu_waves_per_eu(2, 2)))
void qsim_kernel(const float* __restrict__ x,
                 const float* __restrict__ params,
                 float* __restrict__ out) {
  __shared__ vf2 sst[NLDS * NTHR];             // 124 KB LDS-resident state
  __shared__ vf4 xch[4 * NTHR];                // 32 KB exchange buffer (b128)
  __shared__ vf4 utab[NDEPTH * NQ * 4];        // 4 KB pre-expanded coeffs

  const int tid = threadIdx.x;
  const int b = blockIdx.x;

  // ---- per-block gate table: U = RZ(tz) RY(ty) RX(tx), pre-expanded ----
  if (tid < NDEPTH * NQ) {
    const int d = tid / NQ, q = tid % NQ;
    const float a = tanhf(x[b * NQ + q]);
    const float tx = a + params[(d * NQ + q) * 3 + 0];
    const float ty = a + params[(d * NQ + q) * 3 + 1];
    const float tz = a + params[(d * NQ + q) * 3 + 2];
    const float cx = cosf(0.5f * tx), sx = sinf(0.5f * tx);
    const float cy = cosf(0.5f * ty), sy = sinf(0.5f * ty);
    const float cz = cosf(0.5f * tz), sz = sinf(0.5f * tz);
    // M = RY*RX entries (complex), then U = diag(ez, ezc) * M
    const float m00r = cy * cx,  m00i =  sy * sx;
    const float m01r = -sy * cx, m01i = -cy * sx;
    const float m10r = sy * cx,  m10i = -cy * sx;
    const float m11r = cy * cx,  m11i = -sy * sx;
    // ez = cz - i sz ; ezc = cz + i sz
    const float u00r = cz * m00r + sz * m00i, u00i = cz * m00i - sz * m00r;
    const float u01r = cz * m01r + sz * m01i, u01i = cz * m01i - sz * m01r;
    const float u10r = cz * m10r - sz * m10i, u10i = cz * m10i + sz * m10r;
    const float u11r = cz * m11r - sz * m11i, u11i = cz * m11i + sz * m11r;
    vf4* slot = utab + tid * 4;
    // set_0 (parity 0): A=U00, B=U01 ; set_1 (parity 1): A=U11, B=U10
    slot[0] = (vf4){u00r, u00r, -u00i, u00i};
    slot[1] = (vf4){u01r, u01r, -u01i, u01i};
    slot[2] = (vf4){u11r, u11r, -u11i, u11i};
    slot[3] = (vf4){u10r, u10r, -u10i, u10i};
  }

  // ---- state init: |0..0> (amp x=0 lives at tid 0, r 0) ----
  vf2 s[NREG];
  static_for<NREG>([&](auto rc) { s[decltype(rc)::value] = (vf2){0.f, 0.f}; });
  static_for<NLDS>([&](auto ic) {
    sst[decltype(ic)::value * NTHR + tid] = (vf2){0.f, 0.f};
  });
  if (tid == 0) s[0].x = 1.0f;
  __syncthreads();

  // ---- all 64 rotation gates (CNOTs folded into constexpr masks) ----
  apply_all<0, 0>(s, sst, xch, utab, tid);

  // ---- Z expectations, two passes of 8 to cap register pressure ----
  __syncthreads();                 // xch free for reuse as reduction buffer
  float* red = (float*)xch;
  static_for<2>([&](auto hc) {
    constexpr int H = decltype(hc)::value;
    float z[8];
    static_for<8>([&](auto qc) { z[decltype(qc)::value] = 0.f; });
    static_for<NAMP>([&](auto rc) {
      constexpr int r = decltype(rc)::value;
      const vf2 v = getamp<r>(s, sst, tid);
      const float pr = v.x * v.x + v.y * v.y;
      static_for<8>([&](auto qc) {
        constexpr int qq = decltype(qc)::value;
        constexpr int q = 8 * H + qq;
        constexpr bool neg = cpar(r & MK.meas[q]) != 0;
        z[qq] = neg ? (z[qq] - pr) : (z[qq] + pr);
      });
    });
    static_for<8>([&](auto qc) {
      constexpr int qq = decltype(qc)::value;
      constexpr int q = 8 * H + qq;
      const int ptq = __popc(tid & (MK.meas[q] >> 7)) & 1;
      float v = ptq ? -z[qq] : z[qq];
      static_for<6>([&](auto ic) {
        constexpr int sh = 32 >> decltype(ic)::value;
        v += __shfl_xor(v, sh);
      });
      z[qq] = v;
    });
    if ((tid & 63) == 0) {
      const int w = tid >> 6;      // 8 waves
      static_for<8>([&](auto qc) {
        constexpr int qq = decltype(qc)::value;
        red[w * 8 + qq] = z[qq];
      });
    }
    __syncthreads();
    if (tid < 8) {
      float acc = 0.f;
#pragma unroll
      for (int w = 0; w < 8; ++w) acc += red[w * 8 + tid];
      out[b * NQ + 8 * H + tid] = acc;
    }
    __syncthreads();
  });
}

extern "C" void kernel_launch(void* const* d_in, const int* in_sizes, int n_in,
                              void* d_out, int out_size, void* d_ws, size_t ws_size,
                              hipStream_t stream) {
  const float* x      = (const float*)d_in[0];
  const float* params = (const float*)d_in[1];
  float* out          = (float*)d_out;
  qsim_kernel<<<dim3(NBATCH), dim3(NTHR), 0, stream>>>(x, params, out);
}